// Round 7
// baseline (147.240 us; speedup 1.0000x reference)
//
#include <hip/hip_runtime.h>
#include <hip/hip_bf16.h>

#define NFFT   4194304
#define NMODES 2
#define NTAPS  101
#define NVALID (NFFT - NTAPS + 1)   // 4194204
#define N0     (NTAPS / 2)          // 50

constexpr int BLOCK = 256;
constexpr int CPT   = 4;                    // outputs per thread (strided chunks)
constexpr int TILE  = BLOCK * CPT;          // 1024 outputs per block
constexpr int TILE_P = TILE + NTAPS - 1;    // 1124 staged P entries

static __device__ __forceinline__ unsigned short f2bf(float x) {
    __hip_bfloat16 h = __float2bfloat16(x);
    return *reinterpret_cast<unsigned short*>(&h);
}

__global__ __launch_bounds__(BLOCK) void nl_kernel(
    const float* __restrict__ xa,   // d_in[0] big stream (A)
    const float* __restrict__ xb,   // d_in[1] big stream (B)
    const float* __restrict__ W,  const float* __restrict__ b,
    const float* __restrict__ power, unsigned short* __restrict__ out)
{
    __shared__ float2 Pl[TILE_P];

    const int tile_start = blockIdx.x * TILE;

    // ---- stage P = A^2 + B^2 (swap-invariant power) into LDS ----
    for (int idx = threadIdx.x; idx < TILE_P; idx += BLOCK) {
        const int g = tile_start + idx;
        float2 p = make_float2(0.f, 0.f);
        if (g < NFFT) {
            const float2 a = reinterpret_cast<const float2*>(xa)[g];
            const float2 c = reinterpret_cast<const float2*>(xb)[g];
            p.x = a.x * a.x + c.x * c.x;
            p.y = a.y * a.y + c.y * c.y;
        }
        Pl[idx] = p;
    }
    __syncthreads();

    // ---- FIR: phi[n,o] = b[o] + sum_t sum_i P[n+t,i] * W[t,i,o] ----
    const float4* __restrict__ W4 = reinterpret_cast<const float4*>(W);

    float acc[CPT][2];
    const float b0 = b[0], b1 = b[1];
    #pragma unroll
    for (int c = 0; c < CPT; ++c) { acc[c][0] = b0; acc[c][1] = b1; }

    for (int t = 0; t < NTAPS; ++t) {
        const float4 w = W4[t];
        #pragma unroll
        for (int c = 0; c < CPT; ++c) {
            const float2 p = Pl[threadIdx.x + c * BLOCK + t];
            acc[c][0] = fmaf(p.x, w.x, fmaf(p.y, w.z, acc[c][0]));
            acc[c][1] = fmaf(p.x, w.y, fmaf(p.y, w.w, acc[c][1]));
        }
    }

    // ---- phase rotation ----
    // K = GAMMA * DZ * 0.001 * 10^(p/10) / NMODES = 0.066268 * 10^(p/10)
    const float coef = 0.066268f * exp10f(power[0] * 0.1f);

    #pragma unroll
    for (int c = 0; c < CPT; ++c) {
        const int n = tile_start + threadIdx.x + c * BLOCK;
        if (n < NVALID) {
            const float2 A = reinterpret_cast<const float2*>(xa)[n + N0];
            const float2 B = reinterpret_cast<const float2*>(xb)[n + N0];
            const float th0 = acc[c][0] * coef;
            const float th1 = acc[c][1] * coef;
            float s0, c0, s1, c1;
            __sincosf(th0, &s0, &c0);
            __sincosf(th1, &s1, &c1);
            // R7 hypothesis (fits all 6 rounds):
            //   elem0 = B*cos - A*sin,  elem1 = A*cos + B*sin   per (n, mode)
            // (== inputs-swapped + e^{+i theta}  ==  dict inputs + conjugate)
            ushort4 o;
            o.x = f2bf(B.x * c0 - A.x * s0);
            o.y = f2bf(A.x * c0 + B.x * s0);
            o.z = f2bf(B.y * c1 - A.y * s1);
            o.w = f2bf(A.y * c1 + B.y * s1);
            reinterpret_cast<ushort4*>(out)[n] = o;  // interleaved complex layout
        }
    }
}

extern "C" void kernel_launch(void* const* d_in, const int* in_sizes, int n_in,
                              void* d_out, int out_size, void* d_ws, size_t ws_size,
                              hipStream_t stream) {
    // Bind by size (robust): big arrays = x streams, 404 = W, 2 = b, 1 = power.
    const float* big[2] = {nullptr, nullptr};
    const float* W = nullptr; const float* b = nullptr; const float* power = nullptr;
    int nbig = 0;
    for (int i = 0; i < n_in; ++i) {
        const float* p = (const float*)d_in[i];
        const int sz = in_sizes[i];
        if (sz == NFFT * NMODES)       { if (nbig < 2) big[nbig++] = p; }
        else if (sz == NTAPS * NMODES * NMODES) { W = p; }
        else if (sz == NMODES)         { b = p; }
        else if (sz == 1)              { power = p; }
    }

    unsigned short* out = (unsigned short*)d_out;

    const int grid = (NVALID + TILE - 1) / TILE;  // 4096 blocks
    nl_kernel<<<grid, BLOCK, 0, stream>>>(big[0], big[1], W, b, power, out);
}

// Round 8
// 137.679 us; speedup vs baseline: 1.0694x; 1.0694x over previous
//
#include <hip/hip_runtime.h>
#include <hip/hip_bf16.h>

#define NFFT   4194304
#define NMODES 2
#define NTAPS  101
#define NVALID (NFFT - NTAPS + 1)   // 4194204
#define N0     (NTAPS / 2)          // 50

constexpr int BLOCK = 256;
constexpr int CPT   = 8;                    // CONSECUTIVE outputs per thread
constexpr int TILE  = BLOCK * CPT;          // 2048 outputs per block
constexpr int WIN   = TILE + NTAPS - 1;     // 2148 staged P samples
constexpr int PITCH = 269;                  // rows per phase column (odd; max row 268)

static __device__ __forceinline__ unsigned short f2bf(float x) {
    __hip_bfloat16 h = __float2bfloat16(x);
    return *reinterpret_cast<unsigned short*>(&h);
}
static __device__ __forceinline__ unsigned pk(float e0, float e1) {
    return (unsigned)f2bf(e0) | ((unsigned)f2bf(e1) << 16);
}

__global__ __launch_bounds__(BLOCK, 8) void nl_kernel(
    const float* __restrict__ xa,   // d_in[0] big stream (A)
    const float* __restrict__ xb,   // d_in[1] big stream (B)
    const float* __restrict__ W,  const float* __restrict__ b,
    const float* __restrict__ power, unsigned* __restrict__ out)
{
    // P stored phase-swizzled: element e -> Pl[(e&7)*PITCH + (e>>3)]
    __shared__ float2 Pl[CPT * PITCH];

    const int tid = threadIdx.x;
    const int tile_start = blockIdx.x * TILE;

    // ---- stage P = A^2 + B^2 into swizzled LDS ----
    const float2* __restrict__ xa2 = reinterpret_cast<const float2*>(xa);
    const float2* __restrict__ xb2 = reinterpret_cast<const float2*>(xb);
    for (int idx = tid; idx < WIN; idx += BLOCK) {
        const int g = tile_start + idx;
        float2 p = make_float2(0.f, 0.f);
        if (g < NFFT) {
            const float2 a = xa2[g];
            const float2 c = xb2[g];
            p.x = a.x * a.x + c.x * c.x;
            p.y = a.y * a.y + c.y * c.y;
        }
        Pl[(idx & 7) * PITCH + (idx >> 3)] = p;
    }
    __syncthreads();

    // ---- FIR with register sliding window ----
    // Thread handles outputs n = tile_start + tid*8 + c, c=0..7.
    // Window reg w[m&7] holds P element tid*8 + m; one new LDS read per tap.
    float acc[CPT][2];
    const float b0 = b[0], b1 = b[1];
    #pragma unroll
    for (int c = 0; c < CPT; ++c) { acc[c][0] = b0; acc[c][1] = b1; }

    float2 w[8];
    #pragma unroll
    for (int m = 0; m < 7; ++m) w[m] = Pl[m * PITCH + tid];  // prime m=0..6

    const float4* __restrict__ W4 = reinterpret_cast<const float4*>(W);

    // t = 8k + j, k=0..12 (k=12 is the 5-tap tail); all w indices compile-time.
    for (int k = 0; k < 13; ++k) {
        #pragma unroll
        for (int j = 0; j < 8; ++j) {
            if (k == 12 && j >= 5) break;          // 101 taps total
            const int t = k * 8 + j;
            const int ph = (j + 7) & 7;            // phase of new element m=t+7
            w[ph] = Pl[ph * PITCH + (tid + k + ((j + 7) >> 3))];
            const float4 wt = W4[t];               // wave-uniform -> s_load
            #pragma unroll
            for (int c = 0; c < CPT; ++c) {
                const float2 p = w[(j + c) & 7];   // element tid*8 + t + c
                acc[c][0] = fmaf(p.x, wt.x, fmaf(p.y, wt.z, acc[c][0]));
                acc[c][1] = fmaf(p.x, wt.y, fmaf(p.y, wt.w, acc[c][1]));
            }
        }
    }

    // ---- phase rotation + bf16 pack (verified R7 form) ----
    // elem0 = B*cos - A*sin ; elem1 = A*cos + B*sin, theta = acc*coef
    const float coef = 0.066268f * exp10f(power[0] * 0.1f);
    const int base = tile_start + tid * CPT;

    const float4* __restrict__ xa4 = reinterpret_cast<const float4*>(xa); // 2 samples
    const float4* __restrict__ xb4 = reinterpret_cast<const float4*>(xb);
    uint4* __restrict__ out4 = reinterpret_cast<uint4*>(out);             // 2 samples

    #pragma unroll
    for (int cc = 0; cc < 4; ++cc) {
        const int n0 = base + 2 * cc;              // even
        const int c0 = 2 * cc;
        if (n0 + 1 < NVALID) {                     // fast path: both samples valid
            const float4 A = xa4[(n0 + N0) >> 1];  // {s0.m0, s0.m1, s1.m0, s1.m1}
            const float4 B = xb4[(n0 + N0) >> 1];
            float s00, c00, s01, c01, s10, c10, s11, c11;
            __sincosf(acc[c0][0]     * coef, &s00, &c00);
            __sincosf(acc[c0][1]     * coef, &s01, &c01);
            __sincosf(acc[c0 + 1][0] * coef, &s10, &c10);
            __sincosf(acc[c0 + 1][1] * coef, &s11, &c11);
            uint4 o;
            o.x = pk(B.x * c00 - A.x * s00, A.x * c00 + B.x * s00); // s0 mode0
            o.y = pk(B.y * c01 - A.y * s01, A.y * c01 + B.y * s01); // s0 mode1
            o.z = pk(B.z * c10 - A.z * s10, A.z * c10 + B.z * s10); // s1 mode0
            o.w = pk(B.w * c11 - A.w * s11, A.w * c11 + B.w * s11); // s1 mode1
            out4[n0 >> 1] = o;
        } else {
            #pragma unroll
            for (int dc = 0; dc < 2; ++dc) {
                const int n = n0 + dc;
                if (n < NVALID) {
                    const float2 A = xa2[n + N0];
                    const float2 B = xb2[n + N0];
                    float s0, c0s, s1, c1s;
                    __sincosf(acc[c0 + dc][0] * coef, &s0, &c0s);
                    __sincosf(acc[c0 + dc][1] * coef, &s1, &c1s);
                    uint2 o;
                    o.x = pk(B.x * c0s - A.x * s0, A.x * c0s + B.x * s0);
                    o.y = pk(B.y * c1s - A.y * s1, A.y * c1s + B.y * s1);
                    reinterpret_cast<uint2*>(out)[n] = o;
                }
            }
        }
    }
}

extern "C" void kernel_launch(void* const* d_in, const int* in_sizes, int n_in,
                              void* d_out, int out_size, void* d_ws, size_t ws_size,
                              hipStream_t stream) {
    // Bind by size (robust): big arrays = x streams, 404 = W, 2 = b, 1 = power.
    const float* big[2] = {nullptr, nullptr};
    const float* W = nullptr; const float* b = nullptr; const float* power = nullptr;
    int nbig = 0;
    for (int i = 0; i < n_in; ++i) {
        const float* p = (const float*)d_in[i];
        const int sz = in_sizes[i];
        if (sz == NFFT * NMODES)       { if (nbig < 2) big[nbig++] = p; }
        else if (sz == NTAPS * NMODES * NMODES) { W = p; }
        else if (sz == NMODES)         { b = p; }
        else if (sz == 1)              { power = p; }
    }

    unsigned* out = (unsigned*)d_out;
    const int grid = (NVALID + TILE - 1) / TILE;  // 2048 blocks
    nl_kernel<<<grid, BLOCK, 0, stream>>>(big[0], big[1], W, b, power, out);
}